// Round 7
// baseline (413.101 us; speedup 1.0000x reference)
//
#include <hip/hip_runtime.h>
#include <math.h>

#define BB 256
#define LL 256
#define HH 1024
#define NH 16
#define DD 64
#define SCALE 0.5f
#define LN_EPS 1e-5f
#define NEG_BIG (-3.402823466e38f)

// ---------------------------------------------------------------------------
// t_tr: tiled 64x64 transpose with strides, z-planes for 3D permutes.
// ---------------------------------------------------------------------------
__global__ __launch_bounds__(256) void t_tr(const float* __restrict__ in,
                                            float* __restrict__ out, int inRS,
                                            int outRS, int inPlane,
                                            int outPlane) {
  __shared__ float lds[64][68];
  const float* ip = in + (size_t)blockIdx.z * inPlane;
  float* op = out + (size_t)blockIdx.z * outPlane;
  const int rt = blockIdx.y, ct = blockIdx.x;
  const int lr = threadIdx.x >> 4;
  const int lc = (threadIdx.x & 15) * 4;
#pragma unroll
  for (int p = 0; p < 4; p++) {
    float4 v = *(const float4*)(ip + (size_t)(rt * 64 + p * 16 + lr) * inRS +
                                ct * 64 + lc);
    *(float4*)(&lds[p * 16 + lr][lc]) = v;
  }
  __syncthreads();
#pragma unroll
  for (int p = 0; p < 4; p++) {
    float4 v = make_float4(lds[lc + 0][p * 16 + lr], lds[lc + 1][p * 16 + lr],
                           lds[lc + 2][p * 16 + lr], lds[lc + 3][p * 16 + lr]);
    *(float4*)(op + (size_t)(ct * 64 + p * 16 + lr) * outRS + rt * 64 + lc) = v;
  }
}

// ---------------------------------------------------------------------------
// K1: qT[j][b] = bq[j] + sum_i query[b][i]*Wq[j][i]
// ---------------------------------------------------------------------------
__global__ __launch_bounds__(256) void k1_qproj(const float* __restrict__ Wq,
                                                const float* __restrict__ qTT,
                                                const float* __restrict__ bq,
                                                float* __restrict__ qT) {
  __shared__ float smem[10240];
  const int jt = blockIdx.x;
  const int boff = blockIdx.y * 8;
  const int t = threadIdx.x;
  const int g = __builtin_amdgcn_readfirstlane(t >> 6);
  const int ln = t & 63;
  float* kw = smem + g * 2560;
  const float* Wb = Wq + (size_t)(jt * 64) * HH;
  const int srow = ln >> 2, sc = ln & 3;

  float acc[8];
#pragma unroll
  for (int c = 0; c < 8; c++) acc[c] = 0.f;
  float4 pf[4];
#pragma unroll
  for (int p = 0; p < 4; p++)
    pf[p] = *(const float4*)(Wb + (size_t)(p * 16 + srow) * HH + g * 16 + sc * 4);
  int buf = 0;
  for (int T = 0; T < 16; T++) {
    float* kb = kw + buf * 1280;
#pragma unroll
    for (int p = 0; p < 4; p++)
      *(float4*)(kb + ((p * 16 + srow) * 5 + sc) * 4) = pf[p];
    if (T < 15) {
      const int off = (T + 1) * 64 + g * 16 + sc * 4;
#pragma unroll
      for (int p = 0; p < 4; p++)
        pf[p] = *(const float4*)(Wb + (size_t)(p * 16 + srow) * HH + off);
    }
    const int i0 = T * 64 + g * 16;
#pragma unroll
    for (int u = 0; u < 4; u++) {
      float4 kv = *(const float4*)(kb + (ln * 5 + u) * 4);
      const float* q0 = qTT + (size_t)(i0 + u * 4 + 0) * BB + boff;
      const float* q1 = qTT + (size_t)(i0 + u * 4 + 1) * BB + boff;
      const float* q2 = qTT + (size_t)(i0 + u * 4 + 2) * BB + boff;
      const float* q3 = qTT + (size_t)(i0 + u * 4 + 3) * BB + boff;
#pragma unroll
      for (int c = 0; c < 8; c++) {
        acc[c] = fmaf(kv.x, q0[c], acc[c]);
        acc[c] = fmaf(kv.y, q1[c], acc[c]);
        acc[c] = fmaf(kv.z, q2[c], acc[c]);
        acc[c] = fmaf(kv.w, q3[c], acc[c]);
      }
    }
    buf ^= 1;
  }
  __syncthreads();
  float* part = smem;
  *(float4*)(part + g * 768 + ln * 12 + 0) =
      make_float4(acc[0], acc[1], acc[2], acc[3]);
  *(float4*)(part + g * 768 + ln * 12 + 4) =
      make_float4(acc[4], acc[5], acc[6], acc[7]);
  __syncthreads();
  const int j = t & 63, c0 = (t >> 6) * 2;
  float v0 = 0.f, v1 = 0.f;
#pragma unroll
  for (int g2 = 0; g2 < 4; g2++) {
    v0 += part[g2 * 768 + j * 12 + c0];
    v1 += part[g2 * 768 + j * 12 + c0 + 1];
  }
  const int jg = jt * 64 + j;
  const float bias = bq[jg];
  *(float2*)(qT + (size_t)jg * BB + boff + c0) =
      make_float2(v0 + bias, v1 + bias);
}

// ---------------------------------------------------------------------------
// K2: qkT[b][h][i] = SCALE * sum_d qT[h*64+d][b] * Wk[h*64+d][i]
// ---------------------------------------------------------------------------
__global__ __launch_bounds__(256) void k2_qk(const float* __restrict__ qT,
                                             const float* __restrict__ Wk,
                                             float* __restrict__ qkT) {
  const int h = blockIdx.y;
  const int it = blockIdx.x;
  const int il = threadIdx.x & 63;
  const int bs = __builtin_amdgcn_readfirstlane(threadIdx.x >> 6);
  const int i = it * 64 + il;
  const int boff = blockIdx.z * 64 + bs * 16;
  float acc[16];
#pragma unroll
  for (int k = 0; k < 16; k++) acc[k] = 0.f;
#pragma unroll 2
  for (int d = 0; d < DD; d++) {
    float wv = Wk[(size_t)(h * DD + d) * HH + i];
    const float* qrow = qT + (h * DD + d) * BB + boff;  // wave-uniform
#pragma unroll
    for (int k = 0; k < 16; k++) acc[k] = fmaf(qrow[k], wv, acc[k]);
  }
#pragma unroll
  for (int k = 0; k < 16; k++)
    qkT[(size_t)((boff + k) * NH + h) * HH + i] = SCALE * acc[k];
}

// ---------------------------------------------------------------------------
// K3a: scores[b][h][l] = mask ? NEG_BIG : sum_i key[b][l][i]*qk[b][h][i]
// grid (4 lt, 256 b), block 256 = 4 waves.  h split across waves: wave g
// owns h in [4g,4g+4), lane = row l, acc[4], no cross-wave reduce.
// qk staged per-wave per-i-quarter: wave g's 4 h rows x 256 i = 4 KB/stage,
// DOUBLE-BUFFERED (2x16 KB total), register-prefetched one stage ahead.
// Wave-private regions + double buffer -> ZERO barriers.  In-loop qk reads
// are uniform ds_read_b128 broadcasts; key chunks register double-buffered
// (vmcnt only).  [R6 bug: staged 16 KB as if it were all of qk[b]'s 64 KB.]
// ---------------------------------------------------------------------------
__global__ __launch_bounds__(256, 4) void k3a_scores(
    const float* __restrict__ key, const int* __restrict__ mask,
    const float* __restrict__ qkT, float* __restrict__ scoresT) {
  __shared__ float qlds[2][4096];  // [buf][wave g*1024 + ln*16 + p*4]
  const int b = blockIdx.y;
  const int lt = blockIdx.x;
  const int t = threadIdx.x;
  const int g = __builtin_amdgcn_readfirstlane(t >> 6);
  const int ln = t & 63;
  // per-lane staging source: h = g*4 + (ln>>4), i base = (ln&15)*16
  const float* qksrc = qkT + (size_t)b * 16384 +
                       (size_t)(g * 4 + (ln >> 4)) * HH + (ln & 15) * 16;

  const int l = lt * 64 + ln;
  const float* keyrow = key + ((size_t)b * LL + l) * HH;

  float acc[4] = {0.f, 0.f, 0.f, 0.f};

  // stage-0 qk prefetch
  float4 qf[4];
#pragma unroll
  for (int p = 0; p < 4; p++) qf[p] = *(const float4*)(qksrc + p * 4);

  // chunk-0 key prefetch
  float4 p0 = *(const float4*)(keyrow + 0);
  float4 p1 = *(const float4*)(keyrow + 4);
  float4 p2 = *(const float4*)(keyrow + 8);
  float4 p3 = *(const float4*)(keyrow + 12);

  for (int s = 0; s < 4; s++) {
    float* base = qlds[s & 1] + g * 1024;
#pragma unroll
    for (int p = 0; p < 4; p++)
      *(float4*)(base + ln * 16 + p * 4) = qf[p];
    if (s < 3) {
#pragma unroll
      for (int p = 0; p < 4; p++)
        qf[p] = *(const float4*)(qksrc + (s + 1) * 256 + p * 4);
    }
#pragma unroll 2
    for (int c = 0; c < 16; c++) {
      const int cc = s * 16 + c;
      float4 k0 = p0, k1 = p1, k2 = p2, k3 = p3;
      if (cc < 63) {
        const float* nx = keyrow + (cc + 1) * 16;
        p0 = *(const float4*)(nx + 0);
        p1 = *(const float4*)(nx + 4);
        p2 = *(const float4*)(nx + 8);
        p3 = *(const float4*)(nx + 12);
      }
#pragma unroll
      for (int hh = 0; hh < 4; hh++) {
        const float* qr = base + hh * 256 + c * 16;  // uniform -> broadcast
        float4 a0 = *(const float4*)(qr + 0);
        float4 a1 = *(const float4*)(qr + 4);
        float4 a2 = *(const float4*)(qr + 8);
        float4 a3 = *(const float4*)(qr + 12);
        float s2 = acc[hh];
        s2 = fmaf(k0.x, a0.x, s2);
        s2 = fmaf(k0.y, a0.y, s2);
        s2 = fmaf(k0.z, a0.z, s2);
        s2 = fmaf(k0.w, a0.w, s2);
        s2 = fmaf(k1.x, a1.x, s2);
        s2 = fmaf(k1.y, a1.y, s2);
        s2 = fmaf(k1.z, a1.z, s2);
        s2 = fmaf(k1.w, a1.w, s2);
        s2 = fmaf(k2.x, a2.x, s2);
        s2 = fmaf(k2.y, a2.y, s2);
        s2 = fmaf(k2.z, a2.z, s2);
        s2 = fmaf(k2.w, a2.w, s2);
        s2 = fmaf(k3.x, a3.x, s2);
        s2 = fmaf(k3.y, a3.y, s2);
        s2 = fmaf(k3.z, a3.z, s2);
        s2 = fmaf(k3.w, a3.w, s2);
        acc[hh] = s2;
      }
    }
  }

  const int mk = mask[b * LL + l];
#pragma unroll
  for (int hh = 0; hh < 4; hh++) {
    float v = mk ? NEG_BIG : acc[hh];
    scoresT[((size_t)b * NH + g * 4 + hh) * LL + l] = v;
  }
}

// ---------------------------------------------------------------------------
// K3b: in-place softmax over attn[(b*16+h)][256].
// ---------------------------------------------------------------------------
__global__ __launch_bounds__(256) void k3b_softmax(float* __restrict__ attn) {
  const int r = blockIdx.x * 4 + (threadIdx.x >> 6);
  const int lane = threadIdx.x & 63;
  float* rowp = attn + (size_t)r * LL;
  float4 s = *(const float4*)(rowp + lane * 4);
  float m = fmaxf(fmaxf(s.x, s.y), fmaxf(s.z, s.w));
#pragma unroll
  for (int off = 32; off >= 1; off >>= 1) m = fmaxf(m, __shfl_xor(m, off));
  float ex = __expf(s.x - m), ey = __expf(s.y - m), ez = __expf(s.z - m),
        ew = __expf(s.w - m);
  float e = ex + ey + ez + ew;
#pragma unroll
  for (int off = 32; off >= 1; off >>= 1) e += __shfl_xor(e, off);
  float inv = 1.0f / e;
  *(float4*)(rowp + lane * 4) = make_float4(ex * inv, ey * inv, ez * inv, ew * inv);
}

// ---------------------------------------------------------------------------
// K3c: vbar[b][h][d] = sum_l attn[b][h][l] * value[b][l][d]
// grid (16 dt, 256 b), block 256 = 4 waves; h split across waves; attn[b]
// (16 KB, genuinely [16h][256l]) preloaded to LDS once; ds broadcast reads;
// value coalesced dwords.
// ---------------------------------------------------------------------------
__global__ __launch_bounds__(256, 4) void k3c_vbar(
    const float* __restrict__ value, const float* __restrict__ attn,
    float* __restrict__ vbar) {
  __shared__ float alds[4096];  // [16 h][256 l]
  const int b = blockIdx.y;
  const int dt = blockIdx.x;
  const int t = threadIdx.x;
  const int g = __builtin_amdgcn_readfirstlane(t >> 6);
  const int ln = t & 63;
  const float* ab = attn + (size_t)b * 4096;
#pragma unroll
  for (int j = 0; j < 4; j++)
    *(float4*)(alds + j * 1024 + t * 4) =
        *(const float4*)(ab + j * 1024 + t * 4);
  __syncthreads();

  const int d = dt * 64 + ln;
  const float* valb = value + (size_t)b * LL * HH + d;
  const float* aw = alds + (g * 4) * 256;  // wave's 4 h rows (uniform)

  float acc[4] = {0.f, 0.f, 0.f, 0.f};

  for (int l0 = 0; l0 < LL; l0 += 16) {
    float vv[16];
#pragma unroll
    for (int k = 0; k < 16; k++) vv[k] = valb[(size_t)(l0 + k) * HH];
#pragma unroll
    for (int hh = 0; hh < 4; hh++) {
      const float* ar = aw + hh * 256 + l0;  // wave-uniform -> ds broadcast
      float4 a0 = *(const float4*)(ar + 0);
      float4 a1 = *(const float4*)(ar + 4);
      float4 a2 = *(const float4*)(ar + 8);
      float4 a3 = *(const float4*)(ar + 12);
      float s = acc[hh];
      s = fmaf(a0.x, vv[0], s);
      s = fmaf(a0.y, vv[1], s);
      s = fmaf(a0.z, vv[2], s);
      s = fmaf(a0.w, vv[3], s);
      s = fmaf(a1.x, vv[4], s);
      s = fmaf(a1.y, vv[5], s);
      s = fmaf(a1.z, vv[6], s);
      s = fmaf(a1.w, vv[7], s);
      s = fmaf(a2.x, vv[8], s);
      s = fmaf(a2.y, vv[9], s);
      s = fmaf(a2.z, vv[10], s);
      s = fmaf(a2.w, vv[11], s);
      s = fmaf(a3.x, vv[12], s);
      s = fmaf(a3.y, vv[13], s);
      s = fmaf(a3.z, vv[14], s);
      s = fmaf(a3.w, vv[15], s);
      acc[hh] = s;
    }
  }
#pragma unroll
  for (int hh = 0; hh < 4; hh++)
    vbar[((size_t)b * NH + g * 4 + hh) * HH + d] = acc[hh];
}

// ---------------------------------------------------------------------------
// K4: ctxT[j][b] = bv[j] + sum_i vbar[b][j>>6][i] * Wv[j][i]
// ---------------------------------------------------------------------------
__global__ __launch_bounds__(256) void k4_ctx(const float* __restrict__ Wv,
                                              const float* __restrict__ vbarT,
                                              const float* __restrict__ bv,
                                              float* __restrict__ ctxT) {
  __shared__ float smem[10240];
  const int jt = blockIdx.x;
  const int boff = blockIdx.y * 8;
  const int t = threadIdx.x;
  const int g = __builtin_amdgcn_readfirstlane(t >> 6);
  const int ln = t & 63;
  float* kw = smem + g * 2560;
  const float* Wb = Wv + (size_t)(jt * 64) * HH;
  const float* vt = vbarT + (size_t)jt * HH * BB;
  const int srow = ln >> 2, sc = ln & 3;

  float acc[8];
#pragma unroll
  for (int c = 0; c < 8; c++) acc[c] = 0.f;
  float4 pf[4];
#pragma unroll
  for (int p = 0; p < 4; p++)
    pf[p] = *(const float4*)(Wb + (size_t)(p * 16 + srow) * HH + g * 16 + sc * 4);
  int buf = 0;
  for (int T = 0; T < 16; T++) {
    float* kb = kw + buf * 1280;
#pragma unroll
    for (int p = 0; p < 4; p++)
      *(float4*)(kb + ((p * 16 + srow) * 5 + sc) * 4) = pf[p];
    if (T < 15) {
      const int off = (T + 1) * 64 + g * 16 + sc * 4;
#pragma unroll
      for (int p = 0; p < 4; p++)
        pf[p] = *(const float4*)(Wb + (size_t)(p * 16 + srow) * HH + off);
    }
    const int i0 = T * 64 + g * 16;
#pragma unroll
    for (int u = 0; u < 4; u++) {
      float4 kv = *(const float4*)(kb + (ln * 5 + u) * 4);
      const float* q0 = vt + (size_t)(i0 + u * 4 + 0) * BB + boff;
      const float* q1 = vt + (size_t)(i0 + u * 4 + 1) * BB + boff;
      const float* q2 = vt + (size_t)(i0 + u * 4 + 2) * BB + boff;
      const float* q3 = vt + (size_t)(i0 + u * 4 + 3) * BB + boff;
#pragma unroll
      for (int c = 0; c < 8; c++) {
        acc[c] = fmaf(kv.x, q0[c], acc[c]);
        acc[c] = fmaf(kv.y, q1[c], acc[c]);
        acc[c] = fmaf(kv.z, q2[c], acc[c]);
        acc[c] = fmaf(kv.w, q3[c], acc[c]);
      }
    }
    buf ^= 1;
  }
  __syncthreads();
  float* part = smem;
  *(float4*)(part + g * 768 + ln * 12 + 0) =
      make_float4(acc[0], acc[1], acc[2], acc[3]);
  *(float4*)(part + g * 768 + ln * 12 + 4) =
      make_float4(acc[4], acc[5], acc[6], acc[7]);
  __syncthreads();
  const int j = t & 63, c0 = (t >> 6) * 2;
  float v0 = 0.f, v1 = 0.f;
#pragma unroll
  for (int g2 = 0; g2 < 4; g2++) {
    v0 += part[g2 * 768 + j * 12 + c0];
    v1 += part[g2 * 768 + j * 12 + c0 + 1];
  }
  const int jg = jt * 64 + j;
  const float bias = bv[jg];
  *(float2*)(ctxT + (size_t)jg * BB + boff + c0) =
      make_float2(v0 + bias, v1 + bias);
}

// ---------------------------------------------------------------------------
// K5: xws[b][j] = query[b][j] + bf[j] + sum_i ctxT[i][b] * Wf[j][i]
// ---------------------------------------------------------------------------
__global__ __launch_bounds__(256) void k5_outproj(
    const float* __restrict__ Wf, const float* __restrict__ ctxT,
    const float* __restrict__ bf, const float* __restrict__ query,
    float* __restrict__ xws) {
  __shared__ float smem[10240];
  const int jt = blockIdx.x;
  const int boff = blockIdx.y * 8;
  const int t = threadIdx.x;
  const int g = __builtin_amdgcn_readfirstlane(t >> 6);
  const int ln = t & 63;
  float* kw = smem + g * 2560;
  const float* Wb = Wf + (size_t)(jt * 64) * HH;
  const int srow = ln >> 2, sc = ln & 3;

  float acc[8];
#pragma unroll
  for (int c = 0; c < 8; c++) acc[c] = 0.f;
  float4 pf[4];
#pragma unroll
  for (int p = 0; p < 4; p++)
    pf[p] = *(const float4*)(Wb + (size_t)(p * 16 + srow) * HH + g * 16 + sc * 4);
  int buf = 0;
  for (int T = 0; T < 16; T++) {
    float* kb = kw + buf * 1280;
#pragma unroll
    for (int p = 0; p < 4; p++)
      *(float4*)(kb + ((p * 16 + srow) * 5 + sc) * 4) = pf[p];
    if (T < 15) {
      const int off = (T + 1) * 64 + g * 16 + sc * 4;
#pragma unroll
      for (int p = 0; p < 4; p++)
        pf[p] = *(const float4*)(Wb + (size_t)(p * 16 + srow) * HH + off);
    }
    const int i0 = T * 64 + g * 16;
#pragma unroll
    for (int u = 0; u < 4; u++) {
      float4 kv = *(const float4*)(kb + (ln * 5 + u) * 4);
      const float* q0 = ctxT + (size_t)(i0 + u * 4 + 0) * BB + boff;
      const float* q1 = ctxT + (size_t)(i0 + u * 4 + 1) * BB + boff;
      const float* q2 = ctxT + (size_t)(i0 + u * 4 + 2) * BB + boff;
      const float* q3 = ctxT + (size_t)(i0 + u * 4 + 3) * BB + boff;
#pragma unroll
      for (int c = 0; c < 8; c++) {
        acc[c] = fmaf(kv.x, q0[c], acc[c]);
        acc[c] = fmaf(kv.y, q1[c], acc[c]);
        acc[c] = fmaf(kv.z, q2[c], acc[c]);
        acc[c] = fmaf(kv.w, q3[c], acc[c]);
      }
    }
    buf ^= 1;
  }
  __syncthreads();
  float* part = smem;
  *(float4*)(part + g * 768 + ln * 12 + 0) =
      make_float4(acc[0], acc[1], acc[2], acc[3]);
  *(float4*)(part + g * 768 + ln * 12 + 4) =
      make_float4(acc[4], acc[5], acc[6], acc[7]);
  __syncthreads();
  const int j = t & 63, c0 = (t >> 6) * 2;
  float v0 = 0.f, v1 = 0.f;
#pragma unroll
  for (int g2 = 0; g2 < 4; g2++) {
    v0 += part[g2 * 768 + j * 12 + c0];
    v1 += part[g2 * 768 + j * 12 + c0 + 1];
  }
  const int jg = jt * 64 + j;
  const float bias = bf[jg];
  const int b0 = boff + c0;
  xws[(size_t)b0 * HH + jg] = v0 + bias + query[(size_t)b0 * HH + jg];
  xws[(size_t)(b0 + 1) * HH + jg] = v1 + bias + query[(size_t)(b0 + 1) * HH + jg];
}

// ---------------------------------------------------------------------------
// K6: LayerNorm over H, two-pass (exact), block per b.
// ---------------------------------------------------------------------------
__global__ __launch_bounds__(256) void k6_ln(const float* __restrict__ xws,
                                             const float* __restrict__ gamma,
                                             const float* __restrict__ beta,
                                             float* __restrict__ out0) {
  __shared__ float rb[8];
  const int b = blockIdx.x, t = threadIdx.x;
  float4 v = *(const float4*)(xws + (size_t)b * HH + 4 * t);
  float s = v.x + v.y + v.z + v.w;
#pragma unroll
  for (int off = 32; off >= 1; off >>= 1) s += __shfl_xor(s, off);
  if ((t & 63) == 0) rb[t >> 6] = s;
  __syncthreads();
  float mu = (rb[0] + rb[1] + rb[2] + rb[3]) * (1.0f / HH);
  float dx = v.x - mu, dy = v.y - mu, dz = v.z - mu, dw = v.w - mu;
  float q = dx * dx + dy * dy + dz * dz + dw * dw;
#pragma unroll
  for (int off = 32; off >= 1; off >>= 1) q += __shfl_xor(q, off);
  if ((t & 63) == 0) rb[4 + (t >> 6)] = q;
  __syncthreads();
  float var = (rb[4] + rb[5] + rb[6] + rb[7]) * (1.0f / HH);
  float rs = rsqrtf(var + LN_EPS);
  float4 gm = *(const float4*)(gamma + 4 * t);
  float4 bt = *(const float4*)(beta + 4 * t);
  float4 o;
  o.x = dx * rs * gm.x + bt.x;
  o.y = dy * rs * gm.y + bt.y;
  o.z = dz * rs * gm.z + bt.z;
  o.w = dw * rs * gm.w + bt.w;
  *(float4*)(out0 + (size_t)b * HH + 4 * t) = o;
}

extern "C" void kernel_launch(void* const* d_in, const int* in_sizes, int n_in,
                              void* d_out, int out_size, void* d_ws,
                              size_t ws_size, hipStream_t stream) {
  (void)in_sizes; (void)n_in; (void)out_size; (void)ws_size;
  const float* key = (const float*)d_in[0];
  const float* value = (const float*)d_in[1];
  const float* query = (const float*)d_in[2];
  const int* mask = (const int*)d_in[3];
  const float* Wq = (const float*)d_in[4];
  const float* bq = (const float*)d_in[5];
  const float* Wk = (const float*)d_in[6];
  // d_in[7] = bk: softmax-invariant, dropped
  const float* Wv = (const float*)d_in[8];
  const float* bv = (const float*)d_in[9];
  const float* Wf = (const float*)d_in[10];
  const float* bf = (const float*)d_in[11];
  const float* gamma = (const float*)d_in[12];
  const float* beta = (const float*)d_in[13];

  float* out0 = (float*)d_out;      // (B,1,H)
  float* attnOut = out0 + BB * HH;  // (B*NH,1,L): scores -> softmax in place

  char* ws = (char*)d_ws;
  float* qT = (float*)(ws);                  //  1 MB [j][b]
  float* qTT = (float*)(ws + (1 << 20));     //  1 MB [i][b]
  float* qkT = (float*)(ws + (2 << 20));     // 16 MB [b][h][i]
  float* vbar = (float*)(ws + (18 << 20));   // 16 MB [b][h][i]
  float* vbarT = (float*)(ws + (34 << 20));  // 16 MB [h][i][b]
  float* ctxT = (float*)(ws);                //  1 MB [j][b]   (over qT)
  float* xws = (float*)(ws + (1 << 20));     //  1 MB [b][j]   (over qTT)

  t_tr<<<dim3(16, 4, 1), 256, 0, stream>>>(query, qTT, HH, BB, 0, 0);
  k1_qproj<<<dim3(16, 32), 256, 0, stream>>>(Wq, qTT, bq, qT);
  k2_qk<<<dim3(16, 16, 4), 256, 0, stream>>>(qT, Wk, qkT);
  k3a_scores<<<dim3(4, 256), 256, 0, stream>>>(key, mask, qkT, attnOut);
  k3b_softmax<<<dim3(1024), 256, 0, stream>>>(attnOut);
  k3c_vbar<<<dim3(16, 256), 256, 0, stream>>>(value, attnOut, vbar);
  t_tr<<<dim3(16, 4, 16), 256, 0, stream>>>(vbar, vbarT, NH * HH, BB, HH,
                                            HH * BB);
  k4_ctx<<<dim3(16, 32), 256, 0, stream>>>(Wv, vbarT, bv, ctxT);
  k5_outproj<<<dim3(16, 32), 256, 0, stream>>>(Wf, ctxT, bf, query, xws);
  k6_ln<<<dim3(256), 256, 0, stream>>>(xws, gamma, beta, out0);
}